// Round 5
// baseline (92.970 us; speedup 1.0000x reference)
//
#include <hip/hip_runtime.h>

// RandomHingeFern: B=4096, C_in=512, O=1024, D=10, L=2^10=1024
// out[b,o] = weights[o, leaf(b,o)] * min_d |x[b, ord[o,d]] - thr[o,d]|
//
// Mapping: lane <-> b (64 b's per block), o wave-uniform.
//  - xT[c][b] swizzled in LDS: conflict-free staging writes AND compute reads
//  - ord/thr: wave-uniform scalar loads (constant cache, no vector-pipe cost)
//  - weights gather: 64 random leaves within ONE 4KB row (coalesced base)
//  - out: staged in swizzled LDS tile, flushed as coalesced nontemporal float4

#define B_TOT  4096
#define CIN    512
#define O_TOT  1024
#define DEPTH  10
#define LEAVES 1024
#define BT     64     // b-tile = lanes per wave
#define OT     64     // o-tile
#define NTHR   512    // 8 waves

typedef float vf4 __attribute__((ext_vector_type(4)));

__global__ __launch_bounds__(NTHR, 2) void fern_kernel(
    const float* __restrict__ x,          // [B, CIN]
    const float* __restrict__ thresholds, // [O, DEPTH]
    const int*   __restrict__ ordinals,   // [O, DEPTH]
    const float* __restrict__ weights,    // [O, LEAVES]
    float*       __restrict__ out)        // [B, O]
{
    __shared__ float xT[CIN * BT];        // 128 KB, xT[c*64 + (b ^ ((c>>2)&31))]
    __shared__ float osh[BT * OT];        // 16 KB,  osh[b*64 + (o ^ b)]

    const int t    = threadIdx.x;
    const int lane = t & 63;                                   // b_local
    const int wu   = __builtin_amdgcn_readfirstlane(t >> 6);   // wave id, SGPR
    const int b0   = blockIdx.x * BT;
    const int o0   = blockIdx.y * OT;

    // ---- Stage xT: 64 rows x 512 cols = 8192 float4 loads, 16 per thread.
    // Global read fully coalesced; transposed LDS writes swizzled -> 2-way max.
#pragma unroll
    for (int k = 0; k < 16; ++k) {
        const int id = k * NTHR + t;        // 0..8191
        const int r  = id >> 7;             // b row 0..63
        const int c4 = id & 127;            // float4 col
        const vf4 v = *reinterpret_cast<const vf4*>(
            x + (size_t)(b0 + r) * CIN + (c4 << 2));
        const int rs   = r ^ (c4 & 31);     // swizzled b-slot, same for the 4 c's
        const int base = (c4 << 2) * BT + rs;
        xT[base]          = v.x;
        xT[base + BT]     = v.y;
        xT[base + 2 * BT] = v.z;
        xT[base + 3 * BT] = v.w;
    }
    __syncthreads();

    // ---- Compute: wave wu handles o = o0 + wu*8 + i, i = 0..7 (unrolled -> 8
    // independent weight-gather chains in flight per thread).
#pragma unroll
    for (int i = 0; i < 8; ++i) {
        const int ol = wu * 8 + i;          // o_local, wave-uniform (SGPR math)
        const int o  = o0 + ol;
        const int*   op = ordinals   + o * DEPTH;   // uniform -> s_load
        const float* tp = thresholds + o * DEPTH;   // uniform -> s_load

        int   leaf = 0;
        float mm   = 1e30f;
#pragma unroll
        for (int d = 0; d < DEPTH; ++d) {
            const int   ord = op[d];
            const float thr = tp[d];
            const float xv  = xT[ord * BT + (lane ^ ((ord >> 2) & 31))];
            const float mg  = xv - thr;
            leaf = (leaf << 1) | (mg > 0.0f ? 1 : 0);
            mm   = fminf(mm, fabsf(mg));
        }
        const float wv = weights[(size_t)o * LEAVES + leaf];
        osh[lane * OT + (ol ^ lane)] = wv * mm;
    }
    __syncthreads();

    // ---- Flush: coalesced nontemporal float4 stores.
    // thread t: row rb = t>>3; float4-groups g = (t&7) + 8k, k=0..1
    const int rb = t >> 3;
#pragma unroll
    for (int k = 0; k < 2; ++k) {
        const int g  = (t & 7) + (k << 3);  // 0..15
        const int ob = g << 2;              // o_local of .x
        vf4 v;
        v.x = osh[rb * OT + ((ob + 0) ^ rb)];
        v.y = osh[rb * OT + ((ob + 1) ^ rb)];
        v.z = osh[rb * OT + ((ob + 2) ^ rb)];
        v.w = osh[rb * OT + ((ob + 3) ^ rb)];
        __builtin_nontemporal_store(v, reinterpret_cast<vf4*>(
            out + (size_t)(b0 + rb) * O_TOT + o0 + ob));
    }
}

extern "C" void kernel_launch(void* const* d_in, const int* in_sizes, int n_in,
                              void* d_out, int out_size, void* d_ws, size_t ws_size,
                              hipStream_t stream) {
    const float* x          = (const float*)d_in[0];
    const float* thresholds = (const float*)d_in[1];
    const int*   ordinals   = (const int*)d_in[2];
    const float* weights    = (const float*)d_in[3];
    float*       out        = (float*)d_out;

    dim3 grid(B_TOT / BT, O_TOT / OT);     // 64 x 16 = 1024 blocks
    fern_kernel<<<grid, NTHR, 0, stream>>>(x, thresholds, ordinals, weights, out);
}